// Round 20
// baseline (187.249 us; speedup 1.0000x reference)
//
#include <hip/hip_runtime.h>
#include <hip/hip_bf16.h>
#include <math.h>

namespace {
constexpr int kD = 256;      // embed dim
constexpr int kDOUT = 256;   // out dim
constexpr int kNQ = 65536;   // num query nodes
constexpr int kE = 262144;   // edges
constexpr float kAlpha = 0.2f;
constexpr float kEps = 1e-12f;
constexpr int kCap = 16;     // slots per query
constexpr int kOvfMax = 4096;
}

typedef short bf16x8 __attribute__((ext_vector_type(8)));
typedef float f32x4 __attribute__((ext_vector_type(4)));
typedef unsigned short u16x8 __attribute__((ext_vector_type(8)));

// Fused prep: blocks 0..63 zero count (+ovf_n); 64..65 compute c; 66..129 cvt trans.
__global__ __launch_bounds__(256) void prep_kernel(
    const float* __restrict__ a,
    const float* __restrict__ a2,
    const float* __restrict__ trans,
    int4* __restrict__ count4,
    int* __restrict__ ovf_n,
    float* __restrict__ c,
    ushort* __restrict__ tb) {
  const int b = blockIdx.x;
  const int tid = threadIdx.x;
  if (b < 64) {
    count4[b * 256 + tid] = int4{0, 0, 0, 0};
    if (b == 0 && tid == 0) *ovf_n = 0;
  } else if (b < 66) {
    const int j = (b - 64) * 256 + tid;  // 0..511
    float s = 0.f;
#pragma unroll 8
    for (int k = 0; k < kDOUT; ++k) s = fmaf(a[k * (2 * kD) + j], a2[k], s);
    c[j] = s;
  } else {
    const int i = (b - 66) * 256 + tid;  // 0..16383, 4 elems each
    const float4 v = reinterpret_cast<const float4*>(trans)[i];
    union { ushort4 u; __hip_bfloat16 h[4]; } p;
    p.h[0] = __float2bfloat16(v.x);
    p.h[1] = __float2bfloat16(v.y);
    p.h[2] = __float2bfloat16(v.z);
    p.h[3] = __float2bfloat16(v.w);
    reinterpret_cast<ushort4*>(tb)[i] = p.u;
  }
}

// Sweep: reads ONLY query_embed. 4 edges per wave, 16 lanes per edge, each
// lane loads 4 float4 (quarter row). Group-lane-0 claims a capacity-bin slot
// and posts an 8B {edge, qd} store.
__global__ __launch_bounds__(256) void qdot_bin_kernel(
    const float* __restrict__ query_embed,
    const int* __restrict__ qlist,
    const float* __restrict__ c,          // cq at c[256..512)
    int* __restrict__ count,
    int2* __restrict__ bins,
    int* __restrict__ ovf_n,
    int* __restrict__ ovf_q,
    int* __restrict__ ovf_e,
    float* __restrict__ ovf_qd) {
  const int wid = threadIdx.x >> 6;
  const int lane = threadIdx.x & 63;
  const int g = lane >> 4;      // edge slot in wave
  const int l4 = lane & 15;     // lane in 16-group; floats [l4*16, +16)
  const int edge = blockIdx.x * 16 + wid * 4 + g;

  int q = 0;
  if (l4 == 0) q = qlist[edge];   // issued early, in flight under row loads

  const float4* qr = reinterpret_cast<const float4*>(query_embed) + (size_t)edge * 64 + l4 * 4;
  const float4 r0 = qr[0], r1 = qr[1], r2 = qr[2], r3 = qr[3];
  const float4 c0 = reinterpret_cast<const float4*>(c)[64 + l4 * 4 + 0];
  const float4 c1 = reinterpret_cast<const float4*>(c)[64 + l4 * 4 + 1];
  const float4 c2 = reinterpret_cast<const float4*>(c)[64 + l4 * 4 + 2];
  const float4 c3 = reinterpret_cast<const float4*>(c)[64 + l4 * 4 + 3];

  float s = r0.x * c0.x + r0.y * c0.y + r0.z * c0.z + r0.w * c0.w
          + r1.x * c1.x + r1.y * c1.y + r1.z * c1.z + r1.w * c1.w
          + r2.x * c2.x + r2.y * c2.y + r2.z * c2.z + r2.w * c2.w
          + r3.x * c3.x + r3.y * c3.y + r3.z * c3.z + r3.w * c3.w;
#pragma unroll
  for (int off = 1; off < 16; off <<= 1) s += __shfl_xor(s, off, 64);

  if (l4 == 0) {
    const int slot = atomicAdd(&count[q], 1);
    if (slot < kCap) {
      bins[q * kCap + slot] = make_int2(edge, __float_as_int(s));
    } else {
      const int o = atomicAdd(ovf_n, 1);
      if (o < kOvfMax) { ovf_q[o] = q; ovf_e[o] = edge; ovf_qd[o] = s; }
    }
  }
}

// Fused gather + GEMM + elu. Block = 32 queries = two MFMA M-tiles.
// Phase 1: each WAVE owns 8 queries; counts + bin vectors preloaded.
// SOFTWARE-PIPELINED: query i+1's 4 whole-wave row loads are issued before
// query i's reduce/exp chain, hiding random-load latency under VALU work.
// deg>4 spill path loads inline (37%); deg>8 dynamic; deg>16 overflow list.
// Phase 2: wave w takes n-tiles 4w..4w+3; each B fragment feeds both M-tiles.
__global__ __launch_bounds__(256) void gather_gemm_kernel(
    const float* __restrict__ key_embed,
    const float* __restrict__ c,          // ck at c[0..256)
    const int2* __restrict__ bins,
    const int* __restrict__ count,
    const int* __restrict__ ovf_n,
    const int* __restrict__ ovf_q,
    const int* __restrict__ ovf_e,
    const float* __restrict__ ovf_qd,
    const ushort* __restrict__ B,         // trans bf16 (DOUT x D row-major)
    float* __restrict__ out) {
  __shared__ ushort A_lds[32][264];       // +8 pad
  const int wid = threadIdx.x >> 6;
  const int lane = threadIdx.x & 63;
  const int qbase = blockIdx.x * 32 + wid * 8;   // wave owns 8 queries

  // lane covers floats [lane*4, +4) of every row
  const float4 ck = reinterpret_cast<const float4*>(c)[lane];
  const float4* kp = reinterpret_cast<const float4*>(key_embed);

  const int cnt_l = (lane < 8) ? count[qbase + lane] : 0;
  int2 b[8];
  int cnts[8];
#pragma unroll
  for (int i = 0; i < 8; ++i) {
    cnts[i] = __shfl(cnt_l, i, 64);
    const int cmi = min(cnts[i], kCap);
    b[i] = (lane < cmi) ? bins[(size_t)(qbase + i) * kCap + lane] : make_int2(0, 0);
  }

  // prologue: issue query 0's 4 clamped row loads
  float4 L[4];
  {
    const int cl0 = max(min(cnts[0], kCap) - 1, 0);
#pragma unroll
    for (int s = 0; s < 4; ++s) {
      const int eg = __shfl(b[0].x, min(s, cl0), 64);
      L[s] = kp[(size_t)eg * 64 + lane];
    }
  }

#pragma unroll
  for (int i = 0; i < 8; ++i) {
    const int cnt_i = cnts[i];
    const int cmi = min(cnt_i, kCap);
    const int cl = max(cmi - 1, 0);

    // issue NEXT query's loads before this query's compute chain
    float4 Lnext[4];
    if (i < 7) {
      const int cln = max(min(cnts[i + 1], kCap) - 1, 0);
#pragma unroll
      for (int s = 0; s < 4; ++s) {
        const int eg = __shfl(b[i + 1].x, min(s, cln), 64);
        Lnext[s] = kp[(size_t)eg * 64 + lane];
      }
    }

    float4 acc = {0.f, 0.f, 0.f, 0.f};
    float rs = 0.f;

    // common path: slots 0..3 from pipelined registers
#pragma unroll
    for (int s = 0; s < 4; ++s) {
      const float qd = __int_as_float(__shfl(b[i].y, min(s, cl), 64));
      const float4 k4 = L[s];
      float d = k4.x * ck.x + k4.y * ck.y + k4.z * ck.z + k4.w * ck.w;
#pragma unroll
      for (int off = 1; off < 64; off <<= 1) d += __shfl_xor(d, off, 64);
      const float sv = d + qd;
      const float pl = (sv > 0.f) ? sv : kAlpha * sv;   // leaky_relu
      const float ev = (s < cmi) ? __expf(-pl) : 0.f;
      acc.x = fmaf(ev, k4.x, acc.x);
      acc.y = fmaf(ev, k4.y, acc.y);
      acc.z = fmaf(ev, k4.z, acc.z);
      acc.w = fmaf(ev, k4.w, acc.w);
      rs += ev;
    }

    if (cmi > 4) {   // 37%: slots 4..cmi-1, direct loads (wave-uniform loop)
      for (int s = 4; s < cmi; ++s) {
        const int eg = __shfl(b[i].x, s, 64);
        const float qd = __int_as_float(__shfl(b[i].y, s, 64));
        const float4 k4 = kp[(size_t)eg * 64 + lane];
        float d = k4.x * ck.x + k4.y * ck.y + k4.z * ck.z + k4.w * ck.w;
#pragma unroll
        for (int off = 1; off < 64; off <<= 1) d += __shfl_xor(d, off, 64);
        const float sv = d + qd;
        const float pl = (sv > 0.f) ? sv : kAlpha * sv;
        const float ev = __expf(-pl);
        acc.x = fmaf(ev, k4.x, acc.x);
        acc.y = fmaf(ev, k4.y, acc.y);
        acc.z = fmaf(ev, k4.z, acc.z);
        acc.w = fmaf(ev, k4.w, acc.w);
        rs += ev;
      }
    }

    if (cnt_i > kCap) {                // ultra-rare: scan overflow list
      const int q = qbase + i;
      const int n = min(*ovf_n, kOvfMax);
      for (int o = 0; o < n; ++o) {
        if (ovf_q[o] == q) {
          const float4 k4 = kp[(size_t)ovf_e[o] * 64 + lane];
          float d = k4.x * ck.x + k4.y * ck.y + k4.z * ck.z + k4.w * ck.w;
#pragma unroll
          for (int off = 1; off < 64; off <<= 1) d += __shfl_xor(d, off, 64);
          const float sv = d + ovf_qd[o];
          const float pl = (sv > 0.f) ? sv : kAlpha * sv;
          const float ev = __expf(-pl);
          acc.x = fmaf(ev, k4.x, acc.x);
          acc.y = fmaf(ev, k4.y, acc.y);
          acc.z = fmaf(ev, k4.z, acc.z);
          acc.w = fmaf(ev, k4.w, acc.w);
          rs += ev;
        }
      }
    }

    const float inv = 1.0f / ((rs == 0.f) ? kEps : rs);
    union { ushort4 u; __hip_bfloat16 h[4]; } pk;
    pk.h[0] = __float2bfloat16(acc.x * inv);
    pk.h[1] = __float2bfloat16(acc.y * inv);
    pk.h[2] = __float2bfloat16(acc.z * inv);
    pk.h[3] = __float2bfloat16(acc.w * inv);
    *reinterpret_cast<ushort4*>(&A_lds[wid * 8 + i][lane * 4]) = pk.u;

    L[0] = Lnext[0]; L[1] = Lnext[1]; L[2] = Lnext[2]; L[3] = Lnext[3];
  }

  __syncthreads();

  // ---- phase 2: two M-tiles; each B fragment feeds both
  const int m = lane & 15;
  const int kb = (lane >> 4) * 8;
  f32x4 accA[4] = {};
  f32x4 accB[4] = {};

#pragma unroll
  for (int kt = 0; kt < kD; kt += 32) {
    const bf16x8 af0 = *reinterpret_cast<const bf16x8*>(&A_lds[m][kt + kb]);
    const bf16x8 af1 = *reinterpret_cast<const bf16x8*>(&A_lds[16 + m][kt + kb]);
#pragma unroll
    for (int nt = 0; nt < 4; ++nt) {
      const int ntg = wid * 4 + nt;
      const bf16x8 bf =
          *reinterpret_cast<const bf16x8*>(&B[(size_t)(ntg * 16 + m) * kD + kt + kb]);
      accA[nt] = __builtin_amdgcn_mfma_f32_16x16x32_bf16(af0, bf, accA[nt], 0, 0, 0);
      accB[nt] = __builtin_amdgcn_mfma_f32_16x16x32_bf16(af1, bf, accB[nt], 0, 0, 0);
    }
  }

#pragma unroll
  for (int nt = 0; nt < 4; ++nt) {
    const int ntg = wid * 4 + nt;
#pragma unroll
    for (int r = 0; r < 4; ++r) {
      const int rbase = blockIdx.x * 32 + (lane >> 4) * 4 + r;
      const float xa = accA[nt][r];
      out[(size_t)rbase * kDOUT + ntg * 16 + m] = (xa > 0.f) ? xa : expm1f(xa);
      const float xb = accB[nt][r];
      out[(size_t)(rbase + 16) * kDOUT + ntg * 16 + m] = (xb > 0.f) ? xb : expm1f(xb);
    }
  }
}

extern "C" void kernel_launch(void* const* d_in, const int* in_sizes, int n_in,
                              void* d_out, int out_size, void* d_ws, size_t ws_size,
                              hipStream_t stream) {
  // inputs: 0 key_list(int,E) [unused], 1 key_embed(f32,E*256), 2 query_list(int,E),
  //         3 query_embed(f32,E*256), 4 a(f32,256*512), 5 a_2(f32,256), 6 trans(f32,256*256)
  const float* key_embed = (const float*)d_in[1];
  const int* query_list = (const int*)d_in[2];
  const float* query_embed = (const float*)d_in[3];
  const float* a = (const float*)d_in[4];
  const float* a2 = (const float*)d_in[5];
  const float* trans = (const float*)d_in[6];
  float* out = (float*)d_out;

  // workspace (4B units):
  // c[512] | count[NQ] | bins[NQ*16 int2] | transb[256*256 us]
  // | ovf_n[4] | ovf_q[kOvfMax] | ovf_e[kOvfMax] | ovf_qd[kOvfMax]
  float* ws = (float*)d_ws;
  float* c = ws;
  int* count = (int*)(c + 512);
  int2* bins = (int2*)(count + kNQ);
  ushort* transb = (ushort*)(bins + (size_t)kNQ * kCap);
  int* ovf_n = (int*)(transb + (size_t)kDOUT * kD);
  int* ovf_q = ovf_n + 4;
  int* ovf_e = ovf_q + kOvfMax;
  float* ovf_qd = (float*)(ovf_e + kOvfMax);

  prep_kernel<<<130, 256, 0, stream>>>(a, a2, trans, (int4*)count, ovf_n, c, transb);
  qdot_bin_kernel<<<kE / 16, 256, 0, stream>>>(query_embed, query_list, c, count,
                                               bins, ovf_n, ovf_q, ovf_e, ovf_qd);
  gather_gemm_kernel<<<kNQ / 32, 256, 0, stream>>>(key_embed, c, bins, count, ovf_n,
                                                   ovf_q, ovf_e, ovf_qd, transb, out);
}